// Round 4
// baseline (641.048 us; speedup 1.0000x reference)
//
#include <hip/hip_runtime.h>

// ---------------------------------------------------------------------------
// MultimodalFusion: fused 3-dispatch fp16 MFMA GEMMs.
// GEMM structure = round-2-proven double-buffered 1-barrier loop (STAGE next
// tile || COMPUTE current, one __syncthreads per K-tile), downsized to
// 128x128 tile / BK=32 / 4 waves / 32KB static LDS for 4 blocks/CU.
// + RPB weight preprocessing (TWN ternary + exact top-k radix select).
// ---------------------------------------------------------------------------

typedef _Float16 f16x8 __attribute__((ext_vector_type(8)));
typedef float f32x4 __attribute__((ext_vector_type(4)));

__device__ __forceinline__ unsigned short f16b(float v) {
  union { _Float16 h; unsigned short u; } cv; cv.h = (_Float16)v; return cv.u;
}

__device__ __forceinline__ void load_lds16(const void* g, void* l) {
  __builtin_amdgcn_global_load_lds(
      (const __attribute__((address_space(1))) void*)g,
      (__attribute__((address_space(3))) void*)l, 16, 0, 0);
}

__device__ __forceinline__ float sigmoidf_dev(float x) {
  return 1.0f / (1.0f + expf(-x));
}

// ---------------- preprocessing: f32 -> f16 conversion ----------------------
__global__ void f2h(const float* __restrict__ in, unsigned short* __restrict__ out, long n) {
  long n4 = n >> 2;
  for (long i = (long)blockIdx.x * blockDim.x + threadIdx.x; i < n4;
       i += (long)gridDim.x * blockDim.x) {
    float4 v = ((const float4*)in)[i];
    ushort4 o;
    o.x = f16b(v.x); o.y = f16b(v.y); o.z = f16b(v.z); o.w = f16b(v.w);
    ((ushort4*)out)[i] = o;
  }
}

// Wf2 * (1-mix) into W2[:, col0:col0+cols]
__global__ void conv_scaled(const float* __restrict__ W, int rows, int cols,
                            const float* __restrict__ mixp,
                            unsigned short* __restrict__ out, int ldd, int col0) {
  float s = 1.0f - sigmoidf_dev(mixp[0]);
  long S = (long)rows * cols;
  for (long i = (long)blockIdx.x * blockDim.x + threadIdx.x; i < S;
       i += (long)gridDim.x * blockDim.x) {
    int r = (int)(i / cols), c = (int)(i % cols);
    out[(long)r * ldd + col0 + c] = f16b(s * W[i]);
  }
}

__global__ void mk_bias2(const float* __restrict__ bq2, const float* __restrict__ bf2,
                         const float* __restrict__ mixp, float* __restrict__ b2, int n) {
  int i = blockIdx.x * blockDim.x + threadIdx.x;
  if (i < n) {
    float mix = sigmoidf_dev(mixp[0]);
    b2[i] = mix * bq2[i] + (1.0f - mix) * bf2[i];
  }
}

// ---------------- RPB stats: deterministic reductions -----------------------
__global__ void part_abssum(const float4* __restrict__ W4, long n4, float* __restrict__ part) {
  __shared__ float s[256];
  float acc = 0.f;
  for (long i = (long)blockIdx.x * blockDim.x + threadIdx.x; i < n4;
       i += (long)gridDim.x * blockDim.x) {
    float4 v = W4[i];
    acc += fabsf(v.x) + fabsf(v.y) + fabsf(v.z) + fabsf(v.w);
  }
  s[threadIdx.x] = acc; __syncthreads();
  for (int o = 128; o > 0; o >>= 1) {
    if ((int)threadIdx.x < o) s[threadIdx.x] += s[threadIdx.x + o];
    __syncthreads();
  }
  if (threadIdx.x == 0) part[blockIdx.x] = s[0];
}

__global__ void fin_abssum(const float* __restrict__ part, int np, long S,
                           float* __restrict__ scal) {
  __shared__ float s[256];
  float a = 0.f;
  for (int i = threadIdx.x; i < np; i += 256) a += part[i];
  s[threadIdx.x] = a; __syncthreads();
  for (int o = 128; o > 0; o >>= 1) {
    if ((int)threadIdx.x < o) s[threadIdx.x] += s[threadIdx.x + o];
    __syncthreads();
  }
  if (threadIdx.x == 0) scal[0] = 0.7f * (s[0] / (float)S);  // delta
}

__global__ void part_kept(const float* __restrict__ W, long S, const float* __restrict__ scal,
                          float* __restrict__ pb, unsigned* __restrict__ pc) {
  __shared__ float sf[256]; __shared__ unsigned sc[256];
  float delta = scal[0];
  float a = 0.f; unsigned c = 0;
  for (long i = (long)blockIdx.x * blockDim.x + threadIdx.x; i < S;
       i += (long)gridDim.x * blockDim.x) {
    float aw = fabsf(W[i]);
    if (aw > delta) { a += aw; ++c; }
  }
  sf[threadIdx.x] = a; sc[threadIdx.x] = c; __syncthreads();
  for (int o = 128; o > 0; o >>= 1) {
    if ((int)threadIdx.x < o) { sf[threadIdx.x] += sf[threadIdx.x + o]; sc[threadIdx.x] += sc[threadIdx.x + o]; }
    __syncthreads();
  }
  if (threadIdx.x == 0) { pb[blockIdx.x] = sf[0]; pc[blockIdx.x] = sc[0]; }
}

__global__ void fin_kept(const float* __restrict__ pb, const unsigned* __restrict__ pc, int np,
                         float* __restrict__ scal, unsigned* __restrict__ u, unsigned k,
                         unsigned* __restrict__ hist) {
  __shared__ float sf[256]; __shared__ unsigned sc[256];
  float a = 0.f; unsigned c = 0;
  for (int i = threadIdx.x; i < np; i += 256) { a += pb[i]; c += pc[i]; }
  sf[threadIdx.x] = a; sc[threadIdx.x] = c; __syncthreads();
  for (int o = 128; o > 0; o >>= 1) {
    if ((int)threadIdx.x < o) { sf[threadIdx.x] += sf[threadIdx.x + o]; sc[threadIdx.x] += sc[threadIdx.x + o]; }
    __syncthreads();
  }
  if (threadIdx.x == 0) {
    float cnt = (float)sc[0]; if (cnt < 1.f) cnt = 1.f;
    scal[1] = sf[0] / cnt;  // alpha
    u[0] = 0;               // prefix
    u[1] = k;               // k remaining
  }
  hist[threadIdx.x] = 0;
}

// ---------------- radix select of kth largest |res| -------------------------
__global__ void hist_pass(const float* __restrict__ W, long S, const float* __restrict__ scal,
                          const unsigned* __restrict__ u, unsigned* __restrict__ hist, int shift) {
  __shared__ unsigned h[256];
  h[threadIdx.x] = 0; __syncthreads();
  float delta = scal[0], alpha = scal[1];
  unsigned prefix = u[0];
  int hs = shift + 8;
  for (long i = (long)blockIdx.x * blockDim.x + threadIdx.x; i < S;
       i += (long)gridDim.x * blockDim.x) {
    float w = W[i];
    float aw = fabsf(w);
    float wq = (aw > delta) ? copysignf(alpha, w) : 0.0f;
    unsigned ub = __float_as_uint(fabsf(w - wq));
    bool ok = (hs >= 32) || ((ub >> hs) == (prefix >> hs));
    if (ok) atomicAdd(&h[(ub >> shift) & 255u], 1u);
  }
  __syncthreads();
  if (h[threadIdx.x]) atomicAdd(&hist[threadIdx.x], h[threadIdx.x]);
}

__global__ void sel_pass(unsigned* __restrict__ hist, unsigned* __restrict__ u, int shift, int last) {
  __shared__ unsigned h[256];
  int t = threadIdx.x;
  h[t] = hist[t];
  __syncthreads();
  if (t == 0) {
    unsigned krem = u[1];
    unsigned cum = 0, above = 0;
    int bstar = 0;
    for (int b = 255; b >= 0; --b) {
      unsigned nc = cum + h[b];
      if (nc >= krem) { bstar = b; above = cum; break; }
      cum = nc;
    }
    u[0] |= ((unsigned)bstar) << shift;
    u[1] = krem - above;
    if (last) u[2] = u[0];  // kth value bit pattern
  }
  __syncthreads();
  hist[t] = 0;
}

// ---------------- RPB weight writers -----------------------------------------
__global__ void write_rpb(const float* __restrict__ W, long S, const float* __restrict__ scal,
                          const unsigned* __restrict__ u, unsigned short* __restrict__ out) {
  float delta = scal[0], alpha = scal[1];
  unsigned kth = u[2];
  for (long i = (long)blockIdx.x * blockDim.x + threadIdx.x; i < S;
       i += (long)gridDim.x * blockDim.x) {
    float w = W[i];
    float aw = fabsf(w);
    float wq = (aw > delta) ? copysignf(alpha, w) : 0.0f;
    float res = w - wq;
    unsigned ub = __float_as_uint(fabsf(res));
    float v = wq + ((ub >= kth) ? res : 0.0f);
    out[i] = f16b(v);
  }
}

__global__ void write_rpb_scaled(const float* __restrict__ W, int rows, int cols,
                                 const float* __restrict__ scal, const unsigned* __restrict__ u,
                                 const float* __restrict__ mixp,
                                 unsigned short* __restrict__ out, int ldd, int col0) {
  float delta = scal[0], alpha = scal[1];
  unsigned kth = u[2];
  float mix = sigmoidf_dev(mixp[0]);
  long S = (long)rows * cols;
  for (long i = (long)blockIdx.x * blockDim.x + threadIdx.x; i < S;
       i += (long)gridDim.x * blockDim.x) {
    int r = (int)(i / cols), c = (int)(i % cols);
    float w = W[i];
    float aw = fabsf(w);
    float wq = (aw > delta) ? copysignf(alpha, w) : 0.0f;
    float res = w - wq;
    unsigned ub = __float_as_uint(fabsf(res));
    float v = wq + ((ub >= kth) ? res : 0.0f);
    out[(long)r * ldd + col0 + c] = f16b(mix * v);
  }
}

// ---------------- fused GEMM (round-2 structure, 128x128 tile) ---------------
// C[M, sel-cols] = A_sel[M, K_sel] @ B_sel[128-slice, K_sel]^T + bias_sel
// 128x128 tile, BK=32, 256 threads = 4 waves (2x2), per-wave 64x64 output.
// Double-buffered LDS (2 x 16KB), ONE __syncthreads per K-tile.
// Col-block c (128 wide): sel = c>>3 picks operand set, lc = c&7 picks the
// 128-row slice of B / bias. EPI 0: concat+route, 1: relu, 2: f32 out.
struct GemmArgs {
  const unsigned short* A0; const unsigned short* A1; const unsigned short* A2;
  const unsigned short* B0; const unsigned short* B1; const unsigned short* B2;
  const float* c0; const float* c1; const float* c2;
  int K0, K1, K2;
  int nrows;   // grid rows = M / 128
  int ldc;     // output leading dim
  unsigned short* o0; unsigned short* o1; float* oF;
};

template <int EPI>
__global__ __launch_bounds__(256) void gemm4(GemmArgs g) {
  constexpr int AL = 128 * 32 * 2;  // 8192 bytes per A buffer
  constexpr int BL = 128 * 32 * 2;  // 8192 bytes per B buffer
  __shared__ __align__(16) char sm[2 * (AL + BL)];  // 32 KB
  const int tid = threadIdx.x;
  const int wid = tid >> 6;
  const int lane = tid & 63;
  const int wm = wid >> 1, wn = wid & 1;

  // bijective XCD-chunked swizzle (nwg % 8 == 0), row-fastest inside chunk
  const int nwg = gridDim.x;
  const int id = (blockIdx.x & 7) * (nwg >> 3) + (blockIdx.x >> 3);
  const int r = id % g.nrows, c = id / g.nrows;
  const int sel = c >> 3, lc = c & 7;

  const unsigned short* A = sel == 0 ? g.A0 : (sel == 1 ? g.A1 : g.A2);
  const unsigned short* Bw = sel == 0 ? g.B0 : (sel == 1 ? g.B1 : g.B2);
  const float* bias = sel == 0 ? g.c0 : (sel == 1 ? g.c1 : g.c2);
  const int K = sel == 0 ? g.K0 : (sel == 1 ? g.K1 : g.K2);
  const long brow = (long)r * 128;
  const int bRowB = lc * 128;  // row offset into selected B

  f32x4 acc[4][4];
#pragma unroll
  for (int i = 0; i < 4; ++i)
#pragma unroll
    for (int j = 0; j < 4; ++j)
#pragma unroll
      for (int e = 0; e < 4; ++e) acc[i][j][e] = 0.f;

  // staging: per K-tile, A = 8KB, B = 8KB; per wave 2 issues x 1KB each
  const unsigned short* aSrc[2];
  const unsigned short* bSrc[2];
#pragma unroll
  for (int j = 0; j < 2; ++j) {
    int o = j * 4096 + wid * 1024 + lane * 16;   // byte offset in tile
    int row = o >> 6, colb = o & 63;             // 64 B per row (BK=32 f16)
    aSrc[j] = A + (brow + row) * (long)K + (colb >> 1);
    bSrc[j] = Bw + (long)(bRowB + row) * K + (colb >> 1);
  }

  auto STAGE = [&](int buf, int k0) {
    char* lAp = sm + (size_t)buf * AL;
    char* lBp = sm + 2 * AL + (size_t)buf * BL;
#pragma unroll
    for (int j = 0; j < 2; ++j)
      load_lds16(aSrc[j] + k0, lAp + j * 4096 + wid * 1024);
#pragma unroll
    for (int j = 0; j < 2; ++j)
      load_lds16(bSrc[j] + k0, lBp + j * 4096 + wid * 1024);
  };

  const int kb = (lane >> 4) * 16;  // k byte offset of this lane's fragment
  auto COMPUTE = [&](int buf) {
    const char* lAp = sm + (size_t)buf * AL;
    const char* lBp = sm + 2 * AL + (size_t)buf * BL;
    f16x8 a[4], b[4];
#pragma unroll
    for (int m = 0; m < 4; ++m)
      a[m] = *(const f16x8*)(lAp + (wm * 64 + m * 16 + (lane & 15)) * 64 + kb);
#pragma unroll
    for (int n = 0; n < 4; ++n)
      b[n] = *(const f16x8*)(lBp + (wn * 64 + n * 16 + (lane & 15)) * 64 + kb);
#pragma unroll
    for (int m = 0; m < 4; ++m)
#pragma unroll
      for (int n = 0; n < 4; ++n)
        acc[m][n] = __builtin_amdgcn_mfma_f32_16x16x32_f16(a[m], b[n], acc[m][n], 0, 0, 0);
  };

  const int NT = K >> 5;
  STAGE(0, 0);
  __syncthreads();  // vmcnt(0) drain: tile 0 landed
  int cur = 0;
  for (int t = 0; t < NT - 1; ++t) {
    STAGE(cur ^ 1, (t + 1) << 5);  // prefetch next tile into other buffer
    COMPUTE(cur);
    __syncthreads();  // drains vmcnt+lgkmcnt: next tile ready, cur buf free
    cur ^= 1;
  }
  COMPUTE(cur);

  // epilogue: C row = (lane>>4)*4 + e, col = lane&15 (verified m89 layout)
  const int cb = c * 128 + wn * 64;
  const int rb = r * 128 + wm * 64;
  const int bcol0 = bRowB + wn * 64;
#pragma unroll
  for (int i = 0; i < 4; ++i) {
    int r0 = rb + i * 16 + ((lane >> 4) << 2);
#pragma unroll
    for (int j = 0; j < 4; ++j) {
      int ccol = cb + j * 16 + (lane & 15);
      float bb = bias[bcol0 + j * 16 + (lane & 15)];
#pragma unroll
      for (int e = 0; e < 4; ++e) {
        float v = acc[i][j][e] + bb;
        long idx = (long)(r0 + e) * g.ldc + ccol;
        if constexpr (EPI == 0) {
          g.o0[idx] = f16b(v);
          g.o1[idx] = f16b(fabsf(v) >= 0.05f ? v : 0.0f);
        } else if constexpr (EPI == 1) {
          g.o0[idx] = f16b(fmaxf(v, 0.0f));
        } else {
          g.oF[idx] = v;
        }
      }
    }
  }
}

// ---------------------------------------------------------------------------
extern "C" void kernel_launch(void* const* d_in, const int* in_sizes, int n_in,
                              void* d_out, int out_size, void* d_ws, size_t ws_size,
                              hipStream_t stream) {
  const float* xv = (const float*)d_in[0];
  const float* xt = (const float*)d_in[1];
  const float* xa = (const float*)d_in[2];
  const float* Wv = (const float*)d_in[3];
  const float* bv = (const float*)d_in[4];
  const float* Wt = (const float*)d_in[5];
  const float* bt = (const float*)d_in[6];
  const float* Wa = (const float*)d_in[7];
  const float* ba = (const float*)d_in[8];
  const float* Wq1 = (const float*)d_in[9];
  const float* bq1 = (const float*)d_in[10];
  const float* Wq2 = (const float*)d_in[11];
  const float* bq2 = (const float*)d_in[12];
  const float* Wf1 = (const float*)d_in[13];
  const float* bf1 = (const float*)d_in[14];
  const float* Wf2 = (const float*)d_in[15];
  const float* bf2 = (const float*)d_in[16];
  const float* mixp = (const float*)d_in[17];

  const int B = 8192, D = 1024, T = 3072;
  const int Kv = 2048, Kt = 1024, Ka = 512;

  char* w = (char*)d_ws;
  auto alloc = [&](size_t bytes) -> char* {
    char* p = w; w += (bytes + 255) & ~(size_t)255; return p;
  };
  unsigned short* xv_h = (unsigned short*)alloc((size_t)B * Kv * 2);
  unsigned short* xt_h = (unsigned short*)alloc((size_t)B * Kt * 2);
  unsigned short* xa_h = (unsigned short*)alloc((size_t)B * Ka * 2);
  unsigned short* wv_h = (unsigned short*)alloc((size_t)D * Kv * 2);
  unsigned short* wt_h = (unsigned short*)alloc((size_t)D * Kt * 2);
  unsigned short* wa_h = (unsigned short*)alloc((size_t)D * Ka * 2);
  unsigned short* wq1_h = (unsigned short*)alloc((size_t)D * T * 2);
  unsigned short* wf1_h = (unsigned short*)alloc((size_t)D * T * 2);
  unsigned short* w2_h = (unsigned short*)alloc((size_t)D * 2048 * 2);
  unsigned short* concat_h = (unsigned short*)alloc((size_t)B * T * 2);
  unsigned short* routed_h = (unsigned short*)alloc((size_t)B * T * 2);
  unsigned short* a2_h = (unsigned short*)alloc((size_t)B * 2048 * 2);
  float* b2 = (float*)alloc(D * 4);
  float* scal1 = (float*)alloc(64);
  unsigned* u1 = (unsigned*)alloc(64);
  unsigned* hist1 = (unsigned*)alloc(1024);
  float* pa1 = (float*)alloc(1024 * 4);
  float* pb1 = (float*)alloc(1024 * 4);
  unsigned* pc1 = (unsigned*)alloc(1024 * 4);
  float* scal2 = (float*)alloc(64);
  unsigned* u2 = (unsigned*)alloc(64);
  unsigned* hist2 = (unsigned*)alloc(1024);
  float* pa2 = (float*)alloc(1024 * 4);
  float* pb2 = (float*)alloc(1024 * 4);
  unsigned* pc2 = (unsigned*)alloc(1024 * 4);

  // ---- conversions to fp16 ----
  f2h<<<2048, 256, 0, stream>>>(xv, xv_h, (long)B * Kv);
  f2h<<<1024, 256, 0, stream>>>(xt, xt_h, (long)B * Kt);
  f2h<<<512, 256, 0, stream>>>(xa, xa_h, (long)B * Ka);
  f2h<<<256, 256, 0, stream>>>(Wv, wv_h, (long)D * Kv);
  f2h<<<128, 256, 0, stream>>>(Wt, wt_h, (long)D * Kt);
  f2h<<<64, 256, 0, stream>>>(Wa, wa_h, (long)D * Ka);
  f2h<<<512, 256, 0, stream>>>(Wf1, wf1_h, (long)D * T);

  // ---- RPB preprocessing (delta/alpha + exact kth via radix select) ----
  auto rpb_stats = [&](const float* W, long S, unsigned k, float* scal, unsigned* u,
                       unsigned* hist, float* pa, float* pb, unsigned* pc) {
    part_abssum<<<1024, 256, 0, stream>>>((const float4*)W, S / 4, pa);
    fin_abssum<<<1, 256, 0, stream>>>(pa, 1024, S, scal);
    part_kept<<<1024, 256, 0, stream>>>(W, S, scal, pb, pc);
    fin_kept<<<1, 256, 0, stream>>>(pb, pc, 1024, scal, u, k, hist);
    for (int r = 0; r < 4; ++r) {
      hist_pass<<<1024, 256, 0, stream>>>(W, S, scal, u, hist, 24 - 8 * r);
      sel_pass<<<1, 256, 0, stream>>>(hist, u, 24 - 8 * r, r == 3 ? 1 : 0);
    }
  };
  const long S1 = (long)D * T, S2 = (long)D * D;
  rpb_stats(Wq1, S1, (unsigned)(S1 / 10), scal1, u1, hist1, pa1, pb1, pc1);
  write_rpb<<<1024, 256, 0, stream>>>(Wq1, S1, scal1, u1, wq1_h);
  rpb_stats(Wq2, S2, (unsigned)(S2 / 10), scal2, u2, hist2, pa2, pb2, pc2);
  write_rpb_scaled<<<512, 256, 0, stream>>>(Wq2, D, D, scal2, u2, mixp, w2_h, 2048, 0);
  conv_scaled<<<512, 256, 0, stream>>>(Wf2, D, D, mixp, w2_h, 2048, 1024);
  mk_bias2<<<4, 256, 0, stream>>>(bq2, bf2, mixp, b2, D);

  // ---- fused GEMMs (3 dispatches, 128x128 tiles) ----
  // projections -> concat (+route): N = 3072, col-blocks 0-7 v, 8-15 t, 16-23 a
  GemmArgs gp;
  gp.A0 = xv_h; gp.A1 = xt_h; gp.A2 = xa_h;
  gp.B0 = wv_h; gp.B1 = wt_h; gp.B2 = wa_h;
  gp.c0 = bv; gp.c1 = bt; gp.c2 = ba;
  gp.K0 = Kv; gp.K1 = Kt; gp.K2 = Ka;
  gp.nrows = B / 128; gp.ldc = T;
  gp.o0 = concat_h; gp.o1 = routed_h; gp.oF = nullptr;
  gemm4<0><<<24 * (B / 128), 256, 0, stream>>>(gp);

  // hidden -> A2 = [h | g]: N = 2048, col-blocks 0-7 quant, 8-15 full
  GemmArgs gh;
  gh.A0 = routed_h; gh.A1 = concat_h; gh.A2 = routed_h;
  gh.B0 = wq1_h; gh.B1 = wf1_h; gh.B2 = wq1_h;
  gh.c0 = bq1; gh.c1 = bf1; gh.c2 = bq1;
  gh.K0 = T; gh.K1 = T; gh.K2 = T;
  gh.nrows = B / 128; gh.ldc = 2048;
  gh.o0 = a2_h; gh.o1 = nullptr; gh.oF = nullptr;
  gemm4<1><<<16 * (B / 128), 256, 0, stream>>>(gh);

  // fused output: A2 @ [mix*Wq2' | (1-mix)*Wf2]^T + mixed bias
  GemmArgs gf;
  gf.A0 = a2_h; gf.A1 = a2_h; gf.A2 = a2_h;
  gf.B0 = w2_h; gf.B1 = w2_h; gf.B2 = w2_h;
  gf.c0 = b2; gf.c1 = b2; gf.c2 = b2;
  gf.K0 = 2048; gf.K1 = 2048; gf.K2 = 2048;
  gf.nrows = B / 128; gf.ldc = D;
  gf.o0 = nullptr; gf.o1 = nullptr; gf.oF = (float*)d_out;
  gemm4<2><<<8 * (B / 128), 256, 0, stream>>>(gf);
}

// Round 5
// 458.743 us; speedup vs baseline: 1.3974x; 1.3974x over previous
//
#include <hip/hip_runtime.h>

// ---------------------------------------------------------------------------
// MultimodalFusion: fused 3-dispatch fp16 MFMA GEMMs (128x256 tile, BK=32,
// 8 waves, double-buffered 1-barrier loop - round-4-proven schedule) +
// consolidated RPB preprocessing (14 launches total).
// ---------------------------------------------------------------------------

typedef _Float16 f16x8 __attribute__((ext_vector_type(8)));
typedef float f32x4 __attribute__((ext_vector_type(4)));

__device__ __forceinline__ unsigned short f16b(float v) {
  union { _Float16 h; unsigned short u; } cv; cv.h = (_Float16)v; return cv.u;
}

__device__ __forceinline__ void load_lds16(const void* g, void* l) {
  __builtin_amdgcn_global_load_lds(
      (const __attribute__((address_space(1))) void*)g,
      (__attribute__((address_space(3))) void*)l, 16, 0, 0);
}

__device__ __forceinline__ float sigmoidf_dev(float x) {
  return 1.0f / (1.0f + expf(-x));
}

// ---------------- batched f32 -> f16 conversion (7 segments, 1 launch) ------
struct F2HArgs {
  const float* src[7];
  unsigned short* dst[7];
  long cum4[8];  // cumulative float4 counts, cum4[0] = 0
};

__global__ void f2h_all(F2HArgs a) {
  long total = a.cum4[7];
  for (long i = (long)blockIdx.x * blockDim.x + threadIdx.x; i < total;
       i += (long)gridDim.x * blockDim.x) {
    int s = 0;
#pragma unroll
    for (int j = 1; j < 7; ++j) s += (i >= a.cum4[j]) ? 1 : 0;
    long off = i - a.cum4[s];
    float4 v = ((const float4*)a.src[s])[off];
    ushort4 o;
    o.x = f16b(v.x); o.y = f16b(v.y); o.z = f16b(v.z); o.w = f16b(v.w);
    ((ushort4*)a.dst[s])[off] = o;
  }
}

// ---------------- two-weight RPB stats (block-range split 768/256) -----------
#define NB_W1 768
#define NB_TOT 1024

__global__ void part_abssum2(const float* __restrict__ W1, long n41,
                             const float* __restrict__ W2, long n42,
                             float* __restrict__ part) {
  __shared__ float s[256];
  int w = blockIdx.x < NB_W1 ? 0 : 1;
  const float4* W4 = (const float4*)(w ? W2 : W1);
  long n4 = w ? n42 : n41;
  int nb = w ? (NB_TOT - NB_W1) : NB_W1;
  int bid = w ? (int)blockIdx.x - NB_W1 : (int)blockIdx.x;
  float acc = 0.f;
  for (long i = (long)bid * blockDim.x + threadIdx.x; i < n4;
       i += (long)nb * blockDim.x) {
    float4 v = W4[i];
    acc += fabsf(v.x) + fabsf(v.y) + fabsf(v.z) + fabsf(v.w);
  }
  s[threadIdx.x] = acc; __syncthreads();
  for (int o = 128; o > 0; o >>= 1) {
    if ((int)threadIdx.x < o) s[threadIdx.x] += s[threadIdx.x + o];
    __syncthreads();
  }
  if (threadIdx.x == 0) part[blockIdx.x] = s[0];
}

// grid 2: block w sums its region -> scal[w*2+0] = delta_w
__global__ void fin_abssum2(const float* __restrict__ part, long S1, long S2,
                            float* __restrict__ scal) {
  __shared__ float s[256];
  int w = blockIdx.x;
  int lo = w ? NB_W1 : 0, hi = w ? NB_TOT : NB_W1;
  float a = 0.f;
  for (int i = lo + threadIdx.x; i < hi; i += 256) a += part[i];
  s[threadIdx.x] = a; __syncthreads();
  for (int o = 128; o > 0; o >>= 1) {
    if ((int)threadIdx.x < o) s[threadIdx.x] += s[threadIdx.x + o];
    __syncthreads();
  }
  if (threadIdx.x == 0) scal[w * 2] = 0.7f * (s[0] / (float)(w ? S2 : S1));
}

__global__ void part_kept2(const float* __restrict__ W1, long S1,
                           const float* __restrict__ W2, long S2,
                           const float* __restrict__ scal,
                           float* __restrict__ pb, unsigned* __restrict__ pc) {
  __shared__ float sf[256]; __shared__ unsigned sc[256];
  int w = blockIdx.x < NB_W1 ? 0 : 1;
  const float* W = w ? W2 : W1;
  long S = w ? S2 : S1;
  int nb = w ? (NB_TOT - NB_W1) : NB_W1;
  int bid = w ? (int)blockIdx.x - NB_W1 : (int)blockIdx.x;
  float delta = scal[w * 2];
  float a = 0.f; unsigned c = 0;
  for (long i = (long)bid * blockDim.x + threadIdx.x; i < S;
       i += (long)nb * blockDim.x) {
    float aw = fabsf(W[i]);
    if (aw > delta) { a += aw; ++c; }
  }
  sf[threadIdx.x] = a; sc[threadIdx.x] = c; __syncthreads();
  for (int o = 128; o > 0; o >>= 1) {
    if ((int)threadIdx.x < o) { sf[threadIdx.x] += sf[threadIdx.x + o]; sc[threadIdx.x] += sc[threadIdx.x + o]; }
    __syncthreads();
  }
  if (threadIdx.x == 0) { pb[blockIdx.x] = sf[0]; pc[blockIdx.x] = sc[0]; }
}

// grid 2: block w -> alpha_w, u_w init, hist_w zero
__global__ void fin_kept2(const float* __restrict__ pb, const unsigned* __restrict__ pc,
                          float* __restrict__ scal, unsigned* __restrict__ u,
                          unsigned k1, unsigned k2, unsigned* __restrict__ hist) {
  __shared__ float sf[256]; __shared__ unsigned sc[256];
  int w = blockIdx.x;
  int lo = w ? NB_W1 : 0, hi = w ? NB_TOT : NB_W1;
  float a = 0.f; unsigned c = 0;
  for (int i = lo + threadIdx.x; i < hi; i += 256) { a += pb[i]; c += pc[i]; }
  sf[threadIdx.x] = a; sc[threadIdx.x] = c; __syncthreads();
  for (int o = 128; o > 0; o >>= 1) {
    if ((int)threadIdx.x < o) { sf[threadIdx.x] += sf[threadIdx.x + o]; sc[threadIdx.x] += sc[threadIdx.x + o]; }
    __syncthreads();
  }
  if (threadIdx.x == 0) {
    float cnt = (float)sc[0]; if (cnt < 1.f) cnt = 1.f;
    scal[w * 2 + 1] = sf[0] / cnt;  // alpha
    u[w * 4 + 0] = 0;               // prefix
    u[w * 4 + 1] = w ? k2 : k1;     // k remaining
  }
  hist[w * 256 + threadIdx.x] = 0;
}

// ---------------- radix select of kth largest |res|, both weights -----------
__global__ void hist_pass2(const float* __restrict__ W1, long S1,
                           const float* __restrict__ W2, long S2,
                           const float* __restrict__ scal,
                           const unsigned* __restrict__ u,
                           unsigned* __restrict__ hist, int shift) {
  __shared__ unsigned h[256];
  h[threadIdx.x] = 0; __syncthreads();
  int w = blockIdx.x < NB_W1 ? 0 : 1;
  const float* W = w ? W2 : W1;
  long S = w ? S2 : S1;
  int nb = w ? (NB_TOT - NB_W1) : NB_W1;
  int bid = w ? (int)blockIdx.x - NB_W1 : (int)blockIdx.x;
  float delta = scal[w * 2], alpha = scal[w * 2 + 1];
  unsigned prefix = u[w * 4];
  int hs = shift + 8;
  for (long i = (long)bid * blockDim.x + threadIdx.x; i < S;
       i += (long)nb * blockDim.x) {
    float x = W[i];
    float aw = fabsf(x);
    float wq = (aw > delta) ? copysignf(alpha, x) : 0.0f;
    unsigned ub = __float_as_uint(fabsf(x - wq));
    bool ok = (hs >= 32) || ((ub >> hs) == (prefix >> hs));
    if (ok) atomicAdd(&h[(ub >> shift) & 255u], 1u);
  }
  __syncthreads();
  if (h[threadIdx.x]) atomicAdd(&hist[w * 256 + threadIdx.x], h[threadIdx.x]);
}

// grid 2: block w scans hist_w
__global__ void sel_pass2(unsigned* __restrict__ hist, unsigned* __restrict__ u,
                          int shift, int last) {
  __shared__ unsigned h[256];
  int w = blockIdx.x, t = threadIdx.x;
  h[t] = hist[w * 256 + t];
  __syncthreads();
  if (t == 0) {
    unsigned krem = u[w * 4 + 1];
    unsigned cum = 0, above = 0;
    int bstar = 0;
    for (int b = 255; b >= 0; --b) {
      unsigned nc = cum + h[b];
      if (nc >= krem) { bstar = b; above = cum; break; }
      cum = nc;
    }
    u[w * 4 + 0] |= ((unsigned)bstar) << shift;
    u[w * 4 + 1] = krem - above;
    if (last) u[w * 4 + 2] = u[w * 4 + 0];  // kth bit pattern
  }
  __syncthreads();
  hist[w * 256 + t] = 0;
}

// ---------------- fused weight finalize (4 segments, 1 launch) ---------------
struct FinArgs {
  const float* Wq1; const float* Wq2; const float* Wf2;
  const float* bq2; const float* bf2; const float* mixp;
  const float* scal;      // [2][2] delta/alpha per weight
  const unsigned* u;      // [2][4] radix state per weight
  unsigned short* wq1_h;  // 1024 x 3072
  unsigned short* w2_h;   // 1024 x 2048 ([mix*Wq2' | (1-mix)*Wf2])
  float* b2;              // 1024
};

__global__ void finalize_weights(FinArgs a) {
  const long S1 = 3145728, S2 = 1048576, D = 1024;
  float mix = sigmoidf_dev(a.mixp[0]);
  long total = S1 + 2 * S2 + D;
  float d1 = a.scal[0], a1 = a.scal[1];
  float d2 = a.scal[2], a2 = a.scal[3];
  unsigned kth1 = a.u[2], kth2 = a.u[6];
  for (long i = (long)blockIdx.x * blockDim.x + threadIdx.x; i < total;
       i += (long)gridDim.x * blockDim.x) {
    if (i < S1) {
      float x = a.Wq1[i];
      float wq = (fabsf(x) > d1) ? copysignf(a1, x) : 0.0f;
      float res = x - wq;
      float v = wq + ((__float_as_uint(fabsf(res)) >= kth1) ? res : 0.0f);
      a.wq1_h[i] = f16b(v);
    } else if (i < S1 + S2) {
      long j = i - S1; int r = (int)(j >> 10), c = (int)(j & 1023);
      float x = a.Wq2[j];
      float wq = (fabsf(x) > d2) ? copysignf(a2, x) : 0.0f;
      float res = x - wq;
      float v = wq + ((__float_as_uint(fabsf(res)) >= kth2) ? res : 0.0f);
      a.w2_h[(long)r * 2048 + c] = f16b(mix * v);
    } else if (i < S1 + 2 * S2) {
      long j = i - S1 - S2; int r = (int)(j >> 10), c = (int)(j & 1023);
      a.w2_h[(long)r * 2048 + 1024 + c] = f16b((1.0f - mix) * a.Wf2[j]);
    } else {
      long j = i - S1 - 2 * S2;
      a.b2[j] = mix * a.bq2[j] + (1.0f - mix) * a.bf2[j];
    }
  }
}

// ---------------- fused GEMM: 128x256 tile, BK=32, 8 waves, dbuf -------------
// C[M, sel-cols] = A_sel[M, K_sel] @ B_sel[256-slice, K_sel]^T + bias_sel
// 512 threads = 8 waves (2x4), per-wave 64x64 output. Double-buffered LDS
// (2 x 24KB), ONE __syncthreads per K-tile (round-4-proven schedule).
// Col-block c (256 wide): sel = c>>2 picks operand set, lc = c&3 picks the
// 256-row slice of B / bias. EPI 0: concat+route, 1: relu, 2: f32 out.
struct GemmArgs {
  const unsigned short* A0; const unsigned short* A1; const unsigned short* A2;
  const unsigned short* B0; const unsigned short* B1; const unsigned short* B2;
  const float* c0; const float* c1; const float* c2;
  int K0, K1, K2;
  int nrows;   // grid rows = M / 128
  int ldc;     // output leading dim
  unsigned short* o0; unsigned short* o1; float* oF;
};

template <int EPI>
__global__ __launch_bounds__(512) void gemm5(GemmArgs g) {
  constexpr int AL = 128 * 32 * 2;  // 8192 B per A buffer
  constexpr int BL = 256 * 32 * 2;  // 16384 B per B buffer
  __shared__ __align__(16) char sm[2 * AL + 2 * BL];  // 48 KB
  const int tid = threadIdx.x;
  const int wid = tid >> 6;
  const int lane = tid & 63;
  const int wm = wid >> 2, wn = wid & 3;

  // bijective XCD-chunked swizzle (nwg % 8 == 0), row-fastest inside chunk
  const int nwg = gridDim.x;
  const int id = (blockIdx.x & 7) * (nwg >> 3) + (blockIdx.x >> 3);
  const int r = id % g.nrows, c = id / g.nrows;
  const int sel = c >> 2, lc = c & 3;

  const unsigned short* A = sel == 0 ? g.A0 : (sel == 1 ? g.A1 : g.A2);
  const unsigned short* Bw = sel == 0 ? g.B0 : (sel == 1 ? g.B1 : g.B2);
  const float* bias = sel == 0 ? g.c0 : (sel == 1 ? g.c1 : g.c2);
  const int K = sel == 0 ? g.K0 : (sel == 1 ? g.K1 : g.K2);
  const long brow = (long)r * 128;
  const int bRowB = lc * 256;  // row offset into selected B

  f32x4 acc[4][4];
#pragma unroll
  for (int i = 0; i < 4; ++i)
#pragma unroll
    for (int j = 0; j < 4; ++j)
#pragma unroll
      for (int e = 0; e < 4; ++e) acc[i][j][e] = 0.f;

  // staging: A tile 8KB = 1 issue/thread, B tile 16KB = 2 issues/thread
  const int oA = tid * 16;
  const unsigned short* aSrc = A + (brow + (oA >> 6)) * (long)K + ((oA & 63) >> 1);
  const unsigned short* bSrc[2];
#pragma unroll
  for (int j = 0; j < 2; ++j) {
    int o = j * 8192 + tid * 16;
    bSrc[j] = Bw + (long)(bRowB + (o >> 6)) * K + ((o & 63) >> 1);
  }

  auto STAGE = [&](int buf, int k0) {
    load_lds16(aSrc + k0, sm + (size_t)buf * AL + wid * 1024);
#pragma unroll
    for (int j = 0; j < 2; ++j)
      load_lds16(bSrc[j] + k0, sm + 2 * AL + (size_t)buf * BL + j * 8192 + wid * 1024);
  };

  const int kb = (lane >> 4) * 16;  // k byte offset of this lane's fragment
  auto COMPUTE = [&](int buf) {
    const char* lAp = sm + (size_t)buf * AL;
    const char* lBp = sm + 2 * AL + (size_t)buf * BL;
    f16x8 a[4], b[4];
#pragma unroll
    for (int m = 0; m < 4; ++m)
      a[m] = *(const f16x8*)(lAp + (wm * 64 + m * 16 + (lane & 15)) * 64 + kb);
#pragma unroll
    for (int n = 0; n < 4; ++n)
      b[n] = *(const f16x8*)(lBp + (wn * 64 + n * 16 + (lane & 15)) * 64 + kb);
#pragma unroll
    for (int m = 0; m < 4; ++m)
#pragma unroll
      for (int n = 0; n < 4; ++n)
        acc[m][n] = __builtin_amdgcn_mfma_f32_16x16x32_f16(a[m], b[n], acc[m][n], 0, 0, 0);
  };

  const int NT = K >> 5;
  STAGE(0, 0);
  __syncthreads();  // vmcnt(0) drain: tile 0 landed
  int cur = 0;
  for (int t = 0; t < NT - 1; ++t) {
    STAGE(cur ^ 1, (t + 1) << 5);  // prefetch next tile into other buffer
    COMPUTE(cur);
    __syncthreads();  // drains vmcnt+lgkmcnt: next tile ready, cur buf free
    cur ^= 1;
  }
  COMPUTE(cur);

  // epilogue: C row = (lane>>4)*4 + e, col = lane&15 (verified m89 layout)
  const int cb = c * 256 + wn * 64;
  const int rb = r * 128 + wm * 64;
  const int bcol0 = bRowB + wn * 64;
#pragma unroll
  for (int i = 0; i < 4; ++i) {
    int r0 = rb + i * 16 + ((lane >> 4) << 2);
#pragma unroll
    for (int j = 0; j < 4; ++j) {
      int ccol = cb + j * 16 + (lane & 15);
      float bb = bias[bcol0 + j * 16 + (lane & 15)];
#pragma unroll
      for (int e = 0; e < 4; ++e) {
        float v = acc[i][j][e] + bb;
        long idx = (long)(r0 + e) * g.ldc + ccol;
        if constexpr (EPI == 0) {
          g.o0[idx] = f16b(v);
          g.o1[idx] = f16b(fabsf(v) >= 0.05f ? v : 0.0f);
        } else if constexpr (EPI == 1) {
          g.o0[idx] = f16b(fmaxf(v, 0.0f));
        } else {
          g.oF[idx] = v;
        }
      }
    }
  }
}

// ---------------------------------------------------------------------------
extern "C" void kernel_launch(void* const* d_in, const int* in_sizes, int n_in,
                              void* d_out, int out_size, void* d_ws, size_t ws_size,
                              hipStream_t stream) {
  const float* xv = (const float*)d_in[0];
  const float* xt = (const float*)d_in[1];
  const float* xa = (const float*)d_in[2];
  const float* Wv = (const float*)d_in[3];
  const float* bv = (const float*)d_in[4];
  const float* Wt = (const float*)d_in[5];
  const float* bt = (const float*)d_in[6];
  const float* Wa = (const float*)d_in[7];
  const float* ba = (const float*)d_in[8];
  const float* Wq1 = (const float*)d_in[9];
  const float* bq1 = (const float*)d_in[10];
  const float* Wq2 = (const float*)d_in[11];
  const float* bq2 = (const float*)d_in[12];
  const float* Wf1 = (const float*)d_in[13];
  const float* bf1 = (const float*)d_in[14];
  const float* Wf2 = (const float*)d_in[15];
  const float* bf2 = (const float*)d_in[16];
  const float* mixp = (const float*)d_in[17];

  const int B = 8192, D = 1024, T = 3072;
  const int Kv = 2048, Kt = 1024, Ka = 512;
  const long S1 = (long)D * T, S2 = (long)D * D;

  char* w = (char*)d_ws;
  auto alloc = [&](size_t bytes) -> char* {
    char* p = w; w += (bytes + 255) & ~(size_t)255; return p;
  };
  unsigned short* xv_h = (unsigned short*)alloc((size_t)B * Kv * 2);
  unsigned short* xt_h = (unsigned short*)alloc((size_t)B * Kt * 2);
  unsigned short* xa_h = (unsigned short*)alloc((size_t)B * Ka * 2);
  unsigned short* wv_h = (unsigned short*)alloc((size_t)D * Kv * 2);
  unsigned short* wt_h = (unsigned short*)alloc((size_t)D * Kt * 2);
  unsigned short* wa_h = (unsigned short*)alloc((size_t)D * Ka * 2);
  unsigned short* wq1_h = (unsigned short*)alloc((size_t)D * T * 2);
  unsigned short* wf1_h = (unsigned short*)alloc((size_t)D * T * 2);
  unsigned short* w2_h = (unsigned short*)alloc((size_t)D * 2048 * 2);
  unsigned short* concat_h = (unsigned short*)alloc((size_t)B * T * 2);
  unsigned short* routed_h = (unsigned short*)alloc((size_t)B * T * 2);
  unsigned short* a2_h = (unsigned short*)alloc((size_t)B * 2048 * 2);
  float* b2 = (float*)alloc(D * 4);
  float* part = (float*)alloc(1024 * 4);
  float* pb = (float*)alloc(1024 * 4);
  unsigned* pc = (unsigned*)alloc(1024 * 4);
  float* scal = (float*)alloc(64);     // [2][2]
  unsigned* u = (unsigned*)alloc(64);  // [2][4]
  unsigned* hist = (unsigned*)alloc(2 * 256 * 4);

  // ---- batched conversions to fp16 (1 launch) ----
  F2HArgs fa;
  fa.src[0] = xv;  fa.dst[0] = xv_h;
  fa.src[1] = xt;  fa.dst[1] = xt_h;
  fa.src[2] = xa;  fa.dst[2] = xa_h;
  fa.src[3] = Wv;  fa.dst[3] = wv_h;
  fa.src[4] = Wt;  fa.dst[4] = wt_h;
  fa.src[5] = Wa;  fa.dst[5] = wa_h;
  fa.src[6] = Wf1; fa.dst[6] = wf1_h;
  long n4s[7] = {(long)B * Kv / 4, (long)B * Kt / 4, (long)B * Ka / 4,
                 (long)D * Kv / 4, (long)D * Kt / 4, (long)D * Ka / 4, S1 / 4};
  fa.cum4[0] = 0;
  for (int i = 0; i < 7; ++i) fa.cum4[i + 1] = fa.cum4[i] + n4s[i];
  f2h_all<<<2048, 256, 0, stream>>>(fa);

  // ---- two-weight RPB stats + radix select (12 launches) ----
  part_abssum2<<<NB_TOT, 256, 0, stream>>>(Wq1, S1 / 4, Wq2, S2 / 4, part);
  fin_abssum2<<<2, 256, 0, stream>>>(part, S1, S2, scal);
  part_kept2<<<NB_TOT, 256, 0, stream>>>(Wq1, S1, Wq2, S2, scal, pb, pc);
  fin_kept2<<<2, 256, 0, stream>>>(pb, pc, scal, u,
                                   (unsigned)(S1 / 10), (unsigned)(S2 / 10), hist);
  for (int rr = 0; rr < 4; ++rr) {
    hist_pass2<<<NB_TOT, 256, 0, stream>>>(Wq1, S1, Wq2, S2, scal, u, hist, 24 - 8 * rr);
    sel_pass2<<<2, 256, 0, stream>>>(hist, u, 24 - 8 * rr, rr == 3 ? 1 : 0);
  }

  // ---- fused weight finalize (1 launch) ----
  FinArgs fw;
  fw.Wq1 = Wq1; fw.Wq2 = Wq2; fw.Wf2 = Wf2;
  fw.bq2 = bq2; fw.bf2 = bf2; fw.mixp = mixp;
  fw.scal = scal; fw.u = u;
  fw.wq1_h = wq1_h; fw.w2_h = w2_h; fw.b2 = b2;
  finalize_weights<<<1024, 256, 0, stream>>>(fw);

  // ---- fused GEMMs (3 dispatches, 128x256 tiles) ----
  // projections -> concat (+route): N = 3072, col-blocks 0-3 v, 4-7 t, 8-11 a
  GemmArgs gp;
  gp.A0 = xv_h; gp.A1 = xt_h; gp.A2 = xa_h;
  gp.B0 = wv_h; gp.B1 = wt_h; gp.B2 = wa_h;
  gp.c0 = bv; gp.c1 = bt; gp.c2 = ba;
  gp.K0 = Kv; gp.K1 = Kt; gp.K2 = Ka;
  gp.nrows = B / 128; gp.ldc = T;
  gp.o0 = concat_h; gp.o1 = routed_h; gp.oF = nullptr;
  gemm5<0><<<12 * (B / 128), 512, 0, stream>>>(gp);

  // hidden -> A2 = [h | g]: N = 2048, col-blocks 0-3 quant, 4-7 full
  GemmArgs gh;
  gh.A0 = routed_h; gh.A1 = concat_h; gh.A2 = routed_h;
  gh.B0 = wq1_h; gh.B1 = wf1_h; gh.B2 = wq1_h;
  gh.c0 = bq1; gh.c1 = bf1; gh.c2 = bq1;
  gh.K0 = T; gh.K1 = T; gh.K2 = T;
  gh.nrows = B / 128; gh.ldc = 2048;
  gh.o0 = a2_h; gh.o1 = nullptr; gh.oF = nullptr;
  gemm5<1><<<8 * (B / 128), 512, 0, stream>>>(gh);

  // fused output: A2 @ [mix*Wq2' | (1-mix)*Wf2]^T + mixed bias
  GemmArgs gf;
  gf.A0 = a2_h; gf.A1 = a2_h; gf.A2 = a2_h;
  gf.B0 = w2_h; gf.B1 = w2_h; gf.B2 = w2_h;
  gf.c0 = b2; gf.c1 = b2; gf.c2 = b2;
  gf.K0 = 2048; gf.K1 = 2048; gf.K2 = 2048;
  gf.nrows = B / 128; gf.ldc = D;
  gf.o0 = nullptr; gf.o1 = nullptr; gf.oF = (float*)d_out;
  gemm5<2><<<4 * (B / 128), 512, 0, stream>>>(gf);
}

// Round 6
// 424.279 us; speedup vs baseline: 1.5109x; 1.0812x over previous
//
#include <hip/hip_runtime.h>

// ---------------------------------------------------------------------------
// MultimodalFusion: fused 3-dispatch fp16 MFMA GEMMs (128x256 tile, BK=32,
// 8 waves, double-buffered 1-barrier loop - proven schedule) with
// col-fastest XCD chunking (K-balance across XCDs) + consolidated RPB
// preprocessing (12 launches).
// ---------------------------------------------------------------------------

typedef _Float16 f16x8 __attribute__((ext_vector_type(8)));
typedef float f32x4 __attribute__((ext_vector_type(4)));

__device__ __forceinline__ unsigned short f16b(float v) {
  union { _Float16 h; unsigned short u; } cv; cv.h = (_Float16)v; return cv.u;
}

__device__ __forceinline__ void load_lds16(const void* g, void* l) {
  __builtin_amdgcn_global_load_lds(
      (const __attribute__((address_space(1))) void*)g,
      (__attribute__((address_space(3))) void*)l, 16, 0, 0);
}

__device__ __forceinline__ float sigmoidf_dev(float x) {
  return 1.0f / (1.0f + expf(-x));
}

// deterministic 256-thread block reduction over a partial array region
// (identical code everywhere -> bit-identical results across kernels)
__device__ __forceinline__ float reduce_region_f(const float* part, int lo, int hi,
                                                 float* sbuf) {
  float a = 0.f;
  for (int i = lo + threadIdx.x; i < hi; i += 256) a += part[i];
  sbuf[threadIdx.x] = a; __syncthreads();
  for (int o = 128; o > 0; o >>= 1) {
    if ((int)threadIdx.x < o) sbuf[threadIdx.x] += sbuf[threadIdx.x + o];
    __syncthreads();
  }
  float r = sbuf[0];
  __syncthreads();
  return r;
}

// ---------------- batched f32 -> f16 conversion (7 segments, 1 launch) ------
struct F2HArgs {
  const float* src[7];
  unsigned short* dst[7];
  long cum4[8];  // cumulative float4 counts, cum4[0] = 0
};

__global__ void f2h_all(F2HArgs a) {
  long total = a.cum4[7];
  for (long i = (long)blockIdx.x * blockDim.x + threadIdx.x; i < total;
       i += (long)gridDim.x * blockDim.x) {
    int s = 0;
#pragma unroll
    for (int j = 1; j < 7; ++j) s += (i >= a.cum4[j]) ? 1 : 0;
    long off = i - a.cum4[s];
    float4 v = ((const float4*)a.src[s])[off];
    ushort4 o;
    o.x = f16b(v.x); o.y = f16b(v.y); o.z = f16b(v.z); o.w = f16b(v.w);
    ((ushort4*)a.dst[s])[off] = o;
  }
}

// ---------------- two-weight RPB stats (block-range split 768/256) -----------
#define NB_W1 768
#define NB_TOT 1024

// also zeroes hist (blocks 0,1) -- used two kernels later
__global__ void part_abssum2(const float* __restrict__ W1, long n41,
                             const float* __restrict__ W2, long n42,
                             float* __restrict__ part, unsigned* __restrict__ hist) {
  __shared__ float s[256];
  if (blockIdx.x < 2) hist[blockIdx.x * 256 + threadIdx.x] = 0;
  int w = blockIdx.x < NB_W1 ? 0 : 1;
  const float4* W4 = (const float4*)(w ? W2 : W1);
  long n4 = w ? n42 : n41;
  int nb = w ? (NB_TOT - NB_W1) : NB_W1;
  int bid = w ? (int)blockIdx.x - NB_W1 : (int)blockIdx.x;
  float acc = 0.f;
  for (long i = (long)bid * blockDim.x + threadIdx.x; i < n4;
       i += (long)nb * blockDim.x) {
    float4 v = W4[i];
    acc += fabsf(v.x) + fabsf(v.y) + fabsf(v.z) + fabsf(v.w);
  }
  s[threadIdx.x] = acc; __syncthreads();
  for (int o = 128; o > 0; o >>= 1) {
    if ((int)threadIdx.x < o) s[threadIdx.x] += s[threadIdx.x + o];
    __syncthreads();
  }
  if (threadIdx.x == 0) part[blockIdx.x] = s[0];
}

// computes delta per-block from part (redundant, bit-identical), writes scal
__global__ void part_kept2(const float* __restrict__ W1, long S1,
                           const float* __restrict__ W2, long S2,
                           const float* __restrict__ part,
                           float* __restrict__ scal,
                           float* __restrict__ pb, unsigned* __restrict__ pc) {
  __shared__ float sf[256]; __shared__ unsigned sc[256];
  int w = blockIdx.x < NB_W1 ? 0 : 1;
  const float* W = w ? W2 : W1;
  long S = w ? S2 : S1;
  int nb = w ? (NB_TOT - NB_W1) : NB_W1;
  int bid = w ? (int)blockIdx.x - NB_W1 : (int)blockIdx.x;
  float tot = reduce_region_f(part, w ? NB_W1 : 0, w ? NB_TOT : NB_W1, sf);
  float delta = 0.7f * (tot / (float)S);
  if (bid == 0 && threadIdx.x == 0) scal[w * 2] = delta;
  float a = 0.f; unsigned c = 0;
  for (long i = (long)bid * blockDim.x + threadIdx.x; i < S;
       i += (long)nb * blockDim.x) {
    float aw = fabsf(W[i]);
    if (aw > delta) { a += aw; ++c; }
  }
  sf[threadIdx.x] = a; sc[threadIdx.x] = c; __syncthreads();
  for (int o = 128; o > 0; o >>= 1) {
    if ((int)threadIdx.x < o) { sf[threadIdx.x] += sf[threadIdx.x + o]; sc[threadIdx.x] += sc[threadIdx.x + o]; }
    __syncthreads();
  }
  if (threadIdx.x == 0) { pb[blockIdx.x] = sf[0]; pc[blockIdx.x] = sc[0]; }
}

// grid 2: block w -> alpha_w only
__global__ void fin_alpha(const float* __restrict__ pb, const unsigned* __restrict__ pc,
                          float* __restrict__ scal) {
  __shared__ float sf[256]; __shared__ unsigned sc[256];
  int w = blockIdx.x;
  int lo = w ? NB_W1 : 0, hi = w ? NB_TOT : NB_W1;
  float a = 0.f; unsigned c = 0;
  for (int i = lo + threadIdx.x; i < hi; i += 256) { a += pb[i]; c += pc[i]; }
  sf[threadIdx.x] = a; sc[threadIdx.x] = c; __syncthreads();
  for (int o = 128; o > 0; o >>= 1) {
    if ((int)threadIdx.x < o) { sf[threadIdx.x] += sf[threadIdx.x + o]; sc[threadIdx.x] += sc[threadIdx.x + o]; }
    __syncthreads();
  }
  if (threadIdx.x == 0) {
    float cnt = (float)sc[0]; if (cnt < 1.f) cnt = 1.f;
    scal[w * 2 + 1] = sf[0] / cnt;  // alpha
  }
}

// ---------------- radix select of kth largest |res|, both weights -----------
__global__ void hist_pass2(const float* __restrict__ W1, long S1,
                           const float* __restrict__ W2, long S2,
                           const float* __restrict__ scal,
                           const unsigned* __restrict__ u,
                           unsigned* __restrict__ hist, int shift) {
  __shared__ unsigned h[256];
  h[threadIdx.x] = 0; __syncthreads();
  int w = blockIdx.x < NB_W1 ? 0 : 1;
  const float* W = w ? W2 : W1;
  long S = w ? S2 : S1;
  int nb = w ? (NB_TOT - NB_W1) : NB_W1;
  int bid = w ? (int)blockIdx.x - NB_W1 : (int)blockIdx.x;
  float delta = scal[w * 2], alpha = scal[w * 2 + 1];
  unsigned prefix = (shift >= 24) ? 0u : u[w * 4];  // round 0 ignores u
  int hs = shift + 8;
  for (long i = (long)bid * blockDim.x + threadIdx.x; i < S;
       i += (long)nb * blockDim.x) {
    float x = W[i];
    float aw = fabsf(x);
    float wq = (aw > delta) ? copysignf(alpha, x) : 0.0f;
    unsigned ub = __float_as_uint(fabsf(x - wq));
    bool ok = (hs >= 32) || ((ub >> hs) == (prefix >> hs));
    if (ok) atomicAdd(&h[(ub >> shift) & 255u], 1u);
  }
  __syncthreads();
  if (h[threadIdx.x]) atomicAdd(&hist[w * 256 + threadIdx.x], h[threadIdx.x]);
}

// grid 2: block w scans hist_w. round 0: krem from args, u assigned fresh.
__global__ void sel_pass2(unsigned* __restrict__ hist, unsigned* __restrict__ u,
                          int shift, int first, int last,
                          unsigned k1, unsigned k2) {
  __shared__ unsigned h[256];
  int w = blockIdx.x, t = threadIdx.x;
  h[t] = hist[w * 256 + t];
  __syncthreads();
  if (t == 0) {
    unsigned krem = first ? (w ? k2 : k1) : u[w * 4 + 1];
    unsigned cum = 0, above = 0;
    int bstar = 0;
    for (int b = 255; b >= 0; --b) {
      unsigned nc = cum + h[b];
      if (nc >= krem) { bstar = b; above = cum; break; }
      cum = nc;
    }
    unsigned np = ((unsigned)bstar) << shift;
    u[w * 4 + 0] = first ? np : (u[w * 4 + 0] | np);
    u[w * 4 + 1] = krem - above;
    if (last) u[w * 4 + 2] = first ? np : u[w * 4 + 0];  // kth bit pattern
  }
  __syncthreads();
  hist[w * 256 + t] = 0;
}

// ---------------- fused weight finalize (4 segments, 1 launch) ---------------
struct FinArgs {
  const float* Wq1; const float* Wq2; const float* Wf2;
  const float* bq2; const float* bf2; const float* mixp;
  const float* scal;      // [2][2] delta/alpha per weight
  const unsigned* u;      // [2][4] radix state per weight
  unsigned short* wq1_h;  // 1024 x 3072
  unsigned short* w2_h;   // 1024 x 2048 ([mix*Wq2' | (1-mix)*Wf2])
  float* b2;              // 1024
};

__global__ void finalize_weights(FinArgs a) {
  const long S1 = 3145728, S2 = 1048576, D = 1024;
  float mix = sigmoidf_dev(a.mixp[0]);
  long total = S1 + 2 * S2 + D;
  float d1 = a.scal[0], a1 = a.scal[1];
  float d2 = a.scal[2], a2 = a.scal[3];
  unsigned kth1 = a.u[2], kth2 = a.u[6];
  for (long i = (long)blockIdx.x * blockDim.x + threadIdx.x; i < total;
       i += (long)gridDim.x * blockDim.x) {
    if (i < S1) {
      float x = a.Wq1[i];
      float wq = (fabsf(x) > d1) ? copysignf(a1, x) : 0.0f;
      float res = x - wq;
      float v = wq + ((__float_as_uint(fabsf(res)) >= kth1) ? res : 0.0f);
      a.wq1_h[i] = f16b(v);
    } else if (i < S1 + S2) {
      long j = i - S1; int r = (int)(j >> 10), c = (int)(j & 1023);
      float x = a.Wq2[j];
      float wq = (fabsf(x) > d2) ? copysignf(a2, x) : 0.0f;
      float res = x - wq;
      float v = wq + ((__float_as_uint(fabsf(res)) >= kth2) ? res : 0.0f);
      a.w2_h[(long)r * 2048 + c] = f16b(mix * v);
    } else if (i < S1 + 2 * S2) {
      long j = i - S1 - S2; int r = (int)(j >> 10), c = (int)(j & 1023);
      a.w2_h[(long)r * 2048 + 1024 + c] = f16b((1.0f - mix) * a.Wf2[j]);
    } else {
      long j = i - S1 - 2 * S2;
      a.b2[j] = mix * a.bq2[j] + (1.0f - mix) * a.bf2[j];
    }
  }
}

// ---------------- fused GEMM: 128x256 tile, BK=32, 8 waves, dbuf -------------
// C[M, sel-cols] = A_sel[M, K_sel] @ B_sel[256-slice, K_sel]^T + bias_sel
// 512 threads = 8 waves (2x4), per-wave 64x64 output. Double-buffered LDS
// (2 x 24KB), ONE __syncthreads per K-tile (proven schedule).
// XCD chunking col-fastest: each XCD chunk covers ALL col-blocks (K-balance)
// and a contiguous row band (A panel stays L2-hot across col-blocks).
// Col-block c (256 wide): sel = c>>2 picks operand set, lc = c&3 picks the
// 256-row slice of B / bias. EPI 0: concat+route, 1: relu, 2: f32 out.
struct GemmArgs {
  const unsigned short* A0; const unsigned short* A1; const unsigned short* A2;
  const unsigned short* B0; const unsigned short* B1; const unsigned short* B2;
  const float* c0; const float* c1; const float* c2;
  int K0, K1, K2;
  int nrows;   // grid rows = M / 128
  int ldc;     // output leading dim
  unsigned short* o0; unsigned short* o1; float* oF;
};

template <int EPI>
__global__ __launch_bounds__(512) void gemm6(GemmArgs g) {
  constexpr int AL = 128 * 32 * 2;  // 8192 B per A buffer
  constexpr int BL = 256 * 32 * 2;  // 16384 B per B buffer
  __shared__ __align__(16) char sm[2 * AL + 2 * BL];  // 48 KB
  const int tid = threadIdx.x;
  const int wid = tid >> 6;
  const int lane = tid & 63;
  const int wm = wid >> 2, wn = wid & 3;

  // bijective XCD-chunked swizzle (nwg % 8 == 0), col-fastest inside chunk
  const int nwg = gridDim.x;
  const int id = (blockIdx.x & 7) * (nwg >> 3) + (blockIdx.x >> 3);
  const int ncols = nwg / g.nrows;
  const int c = id % ncols, r = id / ncols;
  const int sel = c >> 2, lc = c & 3;

  const unsigned short* A = sel == 0 ? g.A0 : (sel == 1 ? g.A1 : g.A2);
  const unsigned short* Bw = sel == 0 ? g.B0 : (sel == 1 ? g.B1 : g.B2);
  const float* bias = sel == 0 ? g.c0 : (sel == 1 ? g.c1 : g.c2);
  const int K = sel == 0 ? g.K0 : (sel == 1 ? g.K1 : g.K2);
  const long brow = (long)r * 128;
  const int bRowB = lc * 256;  // row offset into selected B

  f32x4 acc[4][4];
#pragma unroll
  for (int i = 0; i < 4; ++i)
#pragma unroll
    for (int j = 0; j < 4; ++j)
#pragma unroll
      for (int e = 0; e < 4; ++e) acc[i][j][e] = 0.f;

  // staging: A tile 8KB = 1 issue/thread, B tile 16KB = 2 issues/thread
  const int oA = tid * 16;
  const unsigned short* aSrc = A + (brow + (oA >> 6)) * (long)K + ((oA & 63) >> 1);
  const unsigned short* bSrc[2];
#pragma unroll
  for (int j = 0; j < 2; ++j) {
    int o = j * 8192 + tid * 16;
    bSrc[j] = Bw + (long)(bRowB + (o >> 6)) * K + ((o & 63) >> 1);
  }

  auto STAGE = [&](int buf, int k0) {
    load_lds16(aSrc + k0, sm + (size_t)buf * AL + wid * 1024);
#pragma unroll
    for (int j = 0; j < 2; ++j)
      load_lds16(bSrc[j] + k0, sm + 2 * AL + (size_t)buf * BL + j * 8192 + wid * 1024);
  };

  const int kb = (lane >> 4) * 16;  // k byte offset of this lane's fragment
  auto COMPUTE = [&](int buf) {
    const char* lAp = sm + (size_t)buf * AL;
    const char* lBp = sm + 2 * AL + (size_t)buf * BL;
    f16x8 a[4], b[4];
#pragma unroll
    for (int m = 0; m < 4; ++m)
      a[m] = *(const f16x8*)(lAp + (wm * 64 + m * 16 + (lane & 15)) * 64 + kb);
#pragma unroll
    for (int n = 0; n < 4; ++n)
      b[n] = *(const f16x8*)(lBp + (wn * 64 + n * 16 + (lane & 15)) * 64 + kb);
#pragma unroll
    for (int m = 0; m < 4; ++m)
#pragma unroll
      for (int n = 0; n < 4; ++n)
        acc[m][n] = __builtin_amdgcn_mfma_f32_16x16x32_f16(a[m], b[n], acc[m][n], 0, 0, 0);
  };

  const int NT = K >> 5;
  STAGE(0, 0);
  __syncthreads();  // vmcnt(0) drain: tile 0 landed
  int cur = 0;
  for (int t = 0; t < NT - 1; ++t) {
    STAGE(cur ^ 1, (t + 1) << 5);  // prefetch next tile into other buffer
    COMPUTE(cur);
    __syncthreads();  // drains vmcnt+lgkmcnt: next tile ready, cur buf free
    cur ^= 1;
  }
  COMPUTE(cur);

  // epilogue: C row = (lane>>4)*4 + e, col = lane&15 (verified m89 layout)
  const int cb = c * 256 + wn * 64;
  const int rb = r * 128 + wm * 64;
  const int bcol0 = bRowB + wn * 64;
#pragma unroll
  for (int i = 0; i < 4; ++i) {
    int r0 = rb + i * 16 + ((lane >> 4) << 2);
#pragma unroll
    for (int j = 0; j < 4; ++j) {
      int ccol = cb + j * 16 + (lane & 15);
      float bb = bias[bcol0 + j * 16 + (lane & 15)];
#pragma unroll
      for (int e = 0; e < 4; ++e) {
        float v = acc[i][j][e] + bb;
        long idx = (long)(r0 + e) * g.ldc + ccol;
        if constexpr (EPI == 0) {
          g.o0[idx] = f16b(v);
          g.o1[idx] = f16b(fabsf(v) >= 0.05f ? v : 0.0f);
        } else if constexpr (EPI == 1) {
          g.o0[idx] = f16b(fmaxf(v, 0.0f));
        } else {
          g.oF[idx] = v;
        }
      }
    }
  }
}

// ---------------------------------------------------------------------------
extern "C" void kernel_launch(void* const* d_in, const int* in_sizes, int n_in,
                              void* d_out, int out_size, void* d_ws, size_t ws_size,
                              hipStream_t stream) {
  const float* xv = (const float*)d_in[0];
  const float* xt = (const float*)d_in[1];
  const float* xa = (const float*)d_in[2];
  const float* Wv = (const float*)d_in[3];
  const float* bv = (const float*)d_in[4];
  const float* Wt = (const float*)d_in[5];
  const float* bt = (const float*)d_in[6];
  const float* Wa = (const float*)d_in[7];
  const float* ba = (const float*)d_in[8];
  const float* Wq1 = (const float*)d_in[9];
  const float* bq1 = (const float*)d_in[10];
  const float* Wq2 = (const float*)d_in[11];
  const float* bq2 = (const float*)d_in[12];
  const float* Wf1 = (const float*)d_in[13];
  const float* bf1 = (const float*)d_in[14];
  const float* Wf2 = (const float*)d_in[15];
  const float* bf2 = (const float*)d_in[16];
  const float* mixp = (const float*)d_in[17];

  const int B = 8192, D = 1024, T = 3072;
  const int Kv = 2048, Kt = 1024, Ka = 512;
  const long S1 = (long)D * T, S2 = (long)D * D;

  char* w = (char*)d_ws;
  auto alloc = [&](size_t bytes) -> char* {
    char* p = w; w += (bytes + 255) & ~(size_t)255; return p;
  };
  unsigned short* xv_h = (unsigned short*)alloc((size_t)B * Kv * 2);
  unsigned short* xt_h = (unsigned short*)alloc((size_t)B * Kt * 2);
  unsigned short* xa_h = (unsigned short*)alloc((size_t)B * Ka * 2);
  unsigned short* wv_h = (unsigned short*)alloc((size_t)D * Kv * 2);
  unsigned short* wt_h = (unsigned short*)alloc((size_t)D * Kt * 2);
  unsigned short* wa_h = (unsigned short*)alloc((size_t)D * Ka * 2);
  unsigned short* wq1_h = (unsigned short*)alloc((size_t)D * T * 2);
  unsigned short* wf1_h = (unsigned short*)alloc((size_t)D * T * 2);
  unsigned short* w2_h = (unsigned short*)alloc((size_t)D * 2048 * 2);
  unsigned short* concat_h = (unsigned short*)alloc((size_t)B * T * 2);
  unsigned short* routed_h = (unsigned short*)alloc((size_t)B * T * 2);
  unsigned short* a2_h = (unsigned short*)alloc((size_t)B * 2048 * 2);
  float* b2 = (float*)alloc(D * 4);
  float* part = (float*)alloc(1024 * 4);
  float* pb = (float*)alloc(1024 * 4);
  unsigned* pc = (unsigned*)alloc(1024 * 4);
  float* scal = (float*)alloc(64);     // [2][2] delta/alpha
  unsigned* u = (unsigned*)alloc(64);  // [2][4]
  unsigned* hist = (unsigned*)alloc(2 * 256 * 4);

  // ---- batched conversions to fp16 (1 launch) ----
  F2HArgs fa;
  fa.src[0] = xv;  fa.dst[0] = xv_h;
  fa.src[1] = xt;  fa.dst[1] = xt_h;
  fa.src[2] = xa;  fa.dst[2] = xa_h;
  fa.src[3] = Wv;  fa.dst[3] = wv_h;
  fa.src[4] = Wt;  fa.dst[4] = wt_h;
  fa.src[5] = Wa;  fa.dst[5] = wa_h;
  fa.src[6] = Wf1; fa.dst[6] = wf1_h;
  long n4s[7] = {(long)B * Kv / 4, (long)B * Kt / 4, (long)B * Ka / 4,
                 (long)D * Kv / 4, (long)D * Kt / 4, (long)D * Ka / 4, S1 / 4};
  fa.cum4[0] = 0;
  for (int i = 0; i < 7; ++i) fa.cum4[i + 1] = fa.cum4[i] + n4s[i];
  f2h_all<<<2048, 256, 0, stream>>>(fa);

  // ---- two-weight RPB stats + radix select (11 launches) ----
  part_abssum2<<<NB_TOT, 256, 0, stream>>>(Wq1, S1 / 4, Wq2, S2 / 4, part, hist);
  part_kept2<<<NB_TOT, 256, 0, stream>>>(Wq1, S1, Wq2, S2, part, scal, pb, pc);
  fin_alpha<<<2, 256, 0, stream>>>(pb, pc, scal);
  for (int rr = 0; rr < 4; ++rr) {
    hist_pass2<<<NB_TOT, 256, 0, stream>>>(Wq1, S1, Wq2, S2, scal, u, hist, 24 - 8 * rr);
    sel_pass2<<<2, 256, 0, stream>>>(hist, u, 24 - 8 * rr, rr == 0 ? 1 : 0,
                                     rr == 3 ? 1 : 0,
                                     (unsigned)(S1 / 10), (unsigned)(S2 / 10));
  }

  // ---- fused weight finalize (1 launch) ----
  FinArgs fw;
  fw.Wq1 = Wq1; fw.Wq2 = Wq2; fw.Wf2 = Wf2;
  fw.bq2 = bq2; fw.bf2 = bf2; fw.mixp = mixp;
  fw.scal = scal; fw.u = u;
  fw.wq1_h = wq1_h; fw.w2_h = w2_h; fw.b2 = b2;
  finalize_weights<<<1024, 256, 0, stream>>>(fw);

  // ---- fused GEMMs (3 dispatches, 128x256 tiles) ----
  // projections -> concat (+route): N = 3072, col-blocks 0-3 v, 4-7 t, 8-11 a
  GemmArgs gp;
  gp.A0 = xv_h; gp.A1 = xt_h; gp.A2 = xa_h;
  gp.B0 = wv_h; gp.B1 = wt_h; gp.B2 = wa_h;
  gp.c0 = bv; gp.c1 = bt; gp.c2 = ba;
  gp.K0 = Kv; gp.K1 = Kt; gp.K2 = Ka;
  gp.nrows = B / 128; gp.ldc = T;
  gp.o0 = concat_h; gp.o1 = routed_h; gp.oF = nullptr;
  gemm6<0><<<12 * (B / 128), 512, 0, stream>>>(gp);

  // hidden -> A2 = [h | g]: N = 2048, col-blocks 0-3 quant, 4-7 full
  GemmArgs gh;
  gh.A0 = routed_h; gh.A1 = concat_h; gh.A2 = routed_h;
  gh.B0 = wq1_h; gh.B1 = wf1_h; gh.B2 = wq1_h;
  gh.c0 = bq1; gh.c1 = bf1; gh.c2 = bq1;
  gh.K0 = T; gh.K1 = T; gh.K2 = T;
  gh.nrows = B / 128; gh.ldc = 2048;
  gh.o0 = a2_h; gh.o1 = nullptr; gh.oF = nullptr;
  gemm6<1><<<8 * (B / 128), 512, 0, stream>>>(gh);

  // fused output: A2 @ [mix*Wq2' | (1-mix)*Wf2]^T + mixed bias
  GemmArgs gf;
  gf.A0 = a2_h; gf.A1 = a2_h; gf.A2 = a2_h;
  gf.B0 = w2_h; gf.B1 = w2_h; gf.B2 = w2_h;
  gf.c0 = b2; gf.c1 = b2; gf.c2 = b2;
  gf.K0 = 2048; gf.K1 = 2048; gf.K2 = 2048;
  gf.nrows = B / 128; gf.ldc = D;
  gf.o0 = nullptr; gf.o1 = nullptr; gf.oF = (float*)d_out;
  gemm6<2><<<4 * (B / 128), 512, 0, stream>>>(gf);
}